// Round 1
// baseline (22147.299 us; speedup 1.0000x reference)
//
#include <hip/hip_runtime.h>

// ============================================================================
// LSTM scan, T=512 B=64 D=H=1024.
// Strategy:
//   K0 k_init : zero barrier counters, bias concat, H0 -> bf16 hbuf[0]
//   K1 k_cvt  : inputs fp32 -> bf16
//   K2 k_wt   : 8x transpose+cvt weights -> WxT/WhT [4096][1024] bf16 (gate-major rows i,f,o,c)
//   K3 k_gemm : x_proj[32768][4096] = inputs @ Wx  (bf16 MFMA, 128x128x64 tiles)
//   K4 k_scan : persistent 256 WGs (4 batch-groups x 64 col-groups), Wh slice in LDS,
//               512 steps with per-batch-group 64-WG spin barrier.
// ============================================================================

typedef unsigned short u16;
typedef unsigned int   u32;
typedef __attribute__((ext_vector_type(8))) short bf16x8;   // 8 bf16 in 4 VGPRs
typedef __attribute__((ext_vector_type(4))) float f32x4;

__device__ __forceinline__ float bf2f(u16 u) {
    union { u32 i; float f; } v; v.i = ((u32)u) << 16; return v.f;
}
__device__ __forceinline__ u16 f2bf(float f) {   // round-to-nearest-even
    union { float f; u32 u; } v; v.f = f;
    u32 u = v.u;
    return (u16)((u + 0x7FFFu + ((u >> 16) & 1u)) >> 16);
}
__device__ __forceinline__ float sigm(float x)   { return 1.f / (1.f + __expf(-x)); }
__device__ __forceinline__ float tanh_f(float x) { return 1.f - 2.f / (1.f + __expf(2.f * x)); }

// ---------------------------------------------------------------------------
// K0: init — hbuf[0] = bf16(H0); bias concat [i|f|o|c]; zero counters.
// grid 64 x 256
// ---------------------------------------------------------------------------
__global__ void k_init(const float* __restrict__ H0,
                       const float* __restrict__ bi, const float* __restrict__ bff,
                       const float* __restrict__ bo, const float* __restrict__ bc,
                       u16* __restrict__ hbuf, float* __restrict__ bias,
                       u32* __restrict__ ctr)
{
    int i = blockIdx.x * 256 + threadIdx.x;      // 0..16383
#pragma unroll
    for (int r = 0; r < 4; ++r) {
        int idx = i + r * 16384;                 // 0..65535
        hbuf[idx] = f2bf(H0[idx]);
    }
    if (i < 4096) {
        const float* bp = (i < 1024) ? bi : (i < 2048) ? bff : (i < 3072) ? bo : bc;
        bias[i] = bp[i & 1023];
    }
    if (i < 256) ctr[i] = 0u;
}

// ---------------------------------------------------------------------------
// K1: inputs fp32 -> bf16 (33.5M elems). grid 32768 x 256, 4 elems/thread.
// ---------------------------------------------------------------------------
__global__ void k_cvt(const float4* __restrict__ in, ushort4* __restrict__ out)
{
    size_t i = (size_t)blockIdx.x * 256 + threadIdx.x;
    float4 v = in[i];
    ushort4 o;
    o.x = f2bf(v.x); o.y = f2bf(v.y); o.z = f2bf(v.z); o.w = f2bf(v.w);
    out[i] = o;
}

// ---------------------------------------------------------------------------
// K2: weight transpose+cvt.  src [1024][1024] fp32 row-major (k-major) ->
// dst [1024][1024] bf16 with rows = output cols (so B-fragments read contiguous K).
// grid (32,32,8), block (32,8). z<4 -> WxT gate z ; z>=4 -> WhT gate z-4.
// ---------------------------------------------------------------------------
__global__ void k_wt(const float* s0, const float* s1, const float* s2, const float* s3,
                     const float* s4, const float* s5, const float* s6, const float* s7,
                     u16* __restrict__ wxT, u16* __restrict__ whT)
{
    const float* srcs[8] = {s0, s1, s2, s3, s4, s5, s6, s7};
    int z = blockIdx.z;
    const float* src = srcs[z];
    u16* dst = (z < 4) ? (wxT + (size_t)z * 1048576) : (whT + (size_t)(z - 4) * 1048576);
    __shared__ float tile[32][33];
    int k0 = blockIdx.x * 32, n0 = blockIdx.y * 32;
    int tx = threadIdx.x, ty = threadIdx.y;
#pragma unroll
    for (int s = 0; s < 4; ++s)
        tile[ty + 8 * s][tx] = src[(size_t)(k0 + ty + 8 * s) * 1024 + n0 + tx];
    __syncthreads();
#pragma unroll
    for (int s = 0; s < 4; ++s)
        dst[(size_t)(n0 + ty + 8 * s) * 1024 + k0 + tx] = f2bf(tile[tx][ty + 8 * s]);
}

// ---------------------------------------------------------------------------
// K3: x_proj GEMM.  C[32768][4096] bf16 = A[32768][1024] @ BT[4096][1024]^T.
// 128x128 tile, BK=64, 4 waves (2x2 of 64x64), mfma 16x16x32 bf16.
// LDS XOR-swizzled via pre-swizzled GLOBAL source + linear LDS write
// (conflict-free writes AND reads).
// grid (256, 32), block 256.
// ---------------------------------------------------------------------------
__global__ __launch_bounds__(256, 2) void k_gemm(const u16* __restrict__ A,
                                                 const u16* __restrict__ BT,
                                                 u16* __restrict__ C)
{
    __shared__ __attribute__((aligned(16))) u16 lsA[128][64];
    __shared__ __attribute__((aligned(16))) u16 lsB[128][64];
    const int tid  = threadIdx.x;
    const int lane = tid & 63;
    const int wv   = tid >> 6;
    const int wm   = wv >> 1, wn = wv & 1;
    const int m0   = blockIdx.x * 128;
    const int n0   = blockIdx.y * 128;
    const int fr   = lane & 15, fq = lane >> 4;
    const int srow = tid >> 3;        // 0..31 (staging row per iter)
    const int sk8  = tid & 7;         // 16B chunk within row

    f32x4 acc[4][4] = {};

    for (int kt = 0; kt < 16; ++kt) {
        const int k0 = kt * 64;
        // ---- stage (pre-swizzled source, linear LDS dest) ----
#pragma unroll
        for (int it = 0; it < 4; ++it) {
            int row = srow + it * 32;
            int kg  = (sk8 ^ (row & 7)) * 8;      // swizzled global chunk
            uint4 va = *(const uint4*)(A  + (size_t)(m0 + row) * 1024 + k0 + kg);
            uint4 vb = *(const uint4*)(BT + (size_t)(n0 + row) * 1024 + k0 + kg);
            *(uint4*)&lsA[row][sk8 * 8] = va;
            *(uint4*)&lsB[row][sk8 * 8] = vb;
        }
        __syncthreads();
        // ---- compute: 2 K-chunks of 32 ----
#pragma unroll
        for (int kc = 0; kc < 2; ++kc) {
            const int kb = kc * 32 + 8 * fq;
            bf16x8 af[4], bfv[4];
#pragma unroll
            for (int i = 0; i < 4; ++i) {
                int ra = 64 * wm + 16 * i + fr;
                af[i] = *(const bf16x8*)&lsA[ra][kb ^ ((ra & 7) * 8)];
            }
#pragma unroll
            for (int j = 0; j < 4; ++j) {
                int rb = 64 * wn + 16 * j + fr;
                bfv[j] = *(const bf16x8*)&lsB[rb][kb ^ ((rb & 7) * 8)];
            }
#pragma unroll
            for (int i = 0; i < 4; ++i)
#pragma unroll
                for (int j = 0; j < 4; ++j)
                    acc[i][j] = __builtin_amdgcn_mfma_f32_16x16x32_bf16(af[i], bfv[j], acc[i][j], 0, 0, 0);
        }
        __syncthreads();
    }
    // ---- epilogue: C layout col=lane&15, row=(lane>>4)*4+reg ----
#pragma unroll
    for (int i = 0; i < 4; ++i) {
        int grow = m0 + 64 * wm + 16 * i + 4 * fq;
#pragma unroll
        for (int j = 0; j < 4; ++j) {
            int gcol = n0 + 64 * wn + 16 * j + fr;
#pragma unroll
            for (int r = 0; r < 4; ++r)
                C[(size_t)(grow + r) * 4096 + gcol] = f2bf(acc[i][j][r]);
        }
    }
}

// ---------------------------------------------------------------------------
// K4: persistent LSTM scan.
// 256 WGs x 512 thr.  WG = (bg 0..3, cg 0..63): batches bg*16..+15, h-cols cg*16..+15.
// LDS: Wh slice [64 gate-rows][1024] bf16 XOR-swizzled (128KB) + partial-G (8KB)
//  -> 1 WG/CU guaranteed (LDS-bound), grid == 256 CUs, spin barrier is safe.
// 8 waves = (gate 0..3) x (K-half 0..1); elementwise on threads 0..255 (1 c-state each).
// ---------------------------------------------------------------------------
__global__ __launch_bounds__(512, 1) void k_scan(const u16* __restrict__ xproj,  // [512][64][4096]
                                                 const u16* __restrict__ whT,    // [4096][1024]
                                                 const float* __restrict__ bias, // [4096]
                                                 const float* __restrict__ C0,   // [64][1024]
                                                 u16* __restrict__ hbuf,         // [2][64][1024]
                                                 u32* __restrict__ ctr,          // [4*64]
                                                 float* __restrict__ out)        // outputs|Hf|Cf
{
    __shared__ __attribute__((aligned(16))) u16  lds_w[64][1024];   // 128 KB
    __shared__ __attribute__((aligned(16))) float lds_g[8][16][16]; // 8 KB

    const int wg  = blockIdx.x;
    const int bg  = wg >> 6;          // batch group 0..3
    const int cg  = wg & 63;          // col group   0..63
    const int b0  = bg * 16;
    const int j0  = cg * 16;
    const int tid = threadIdx.x;
    const int lane = tid & 63;
    const int wv  = tid >> 6;         // 0..7
    const int g   = wv & 3;           // gate
    const int kh  = wv >> 2;          // K-half
    const int fr  = lane & 15;
    const int fq  = lane >> 4;

    // ---- load Wh slice into LDS, swizzled: elem (n,k) at [n][k ^ ((n&7)*8)] ----
    for (int it = 0; it < 16; ++it) {
        int idx = tid + it * 512;               // uint4 index, 8192 total
        int row = idx >> 7;                     // 0..63   (gate*16 + jj)
        int k8  = idx & 127;
        int gg  = row >> 4, jj = row & 15;
        uint4 v = *((const uint4*)(whT + ((size_t)(gg * 1024 + j0 + jj) << 10)) + k8);
        *(uint4*)&lds_w[row][(k8 * 8) ^ ((row & 7) * 8)] = v;
    }

    // ---- per-thread recurrent state (threads 0..255) ----
    const int eb = tid >> 4;   // local batch 0..15
    const int ej = tid & 15;   // local h-col 0..15
    float c_state = 0.f;
    float bia[4] = {0.f, 0.f, 0.f, 0.f};
    if (tid < 256) {
        c_state = C0[(size_t)(b0 + eb) * 1024 + j0 + ej];
#pragma unroll
        for (int q = 0; q < 4; ++q) bia[q] = bias[q * 1024 + j0 + ej];
    }
    __syncthreads();

    const int rB = g * 16 + fr;                 // lds_w row for B-fragment
    const int swzB = (rB & 7) * 8;
    const int base_k = kh * 512 + 8 * fq;
    u32* myctr = &ctr[bg * 64];                 // 256B-spaced group counters

    for (int t = 0; t < 512; ++t) {
        const int p = t & 1;
        const u16* hb = hbuf + (size_t)p * 65536;

        // prefetch xg early (independent of h) — latency hides under MFMA phase
        float xg[4] = {0.f, 0.f, 0.f, 0.f};
        if (tid < 256) {
            const u16* xp = xproj + ((size_t)t * 64 + (b0 + eb)) * 4096 + j0 + ej;
#pragma unroll
            for (int q = 0; q < 4; ++q) xg[q] = bf2f(xp[q * 1024]);
        }

        // ---- A-fragments: h rows from global (L2-resident, shared across waves) ----
        bf16x8 af[16];
        const u16* arow = hb + (size_t)(b0 + fr) * 1024 + base_k;
#pragma unroll
        for (int kk = 0; kk < 16; ++kk)
            af[kk] = *(const bf16x8*)(arow + kk * 32);

        // ---- MFMA: one 16x16 tile per wave (gate g, K-half kh) ----
        f32x4 acc = {0.f, 0.f, 0.f, 0.f};
#pragma unroll
        for (int kk = 0; kk < 16; ++kk) {
            int kb = (base_k + kk * 32) ^ swzB;
            bf16x8 bfv = *(const bf16x8*)&lds_w[rB][kb];
            acc = __builtin_amdgcn_mfma_f32_16x16x32_bf16(af[kk], bfv, acc, 0, 0, 0);
        }
#pragma unroll
        for (int r = 0; r < 4; ++r)
            lds_g[wv][4 * fq + r][fr] = acc[r];
        __syncthreads();

        // ---- elementwise LSTM cell (threads 0..255) ----
        if (tid < 256) {
            float gate[4];
#pragma unroll
            for (int q = 0; q < 4; ++q)
                gate[q] = lds_g[q][eb][ej] + lds_g[4 + q][eb][ej] + xg[q] + bia[q];
            float i_ = sigm(gate[0]);
            float f_ = sigm(gate[1]);
            float o_ = sigm(gate[2]);
            float g_ = tanh_f(gate[3]);
            c_state = f_ * c_state + i_ * g_;
            float h_ = o_ * tanh_f(c_state);

            size_t hidx = (size_t)(b0 + eb) * 1024 + j0 + ej;
            hbuf[(size_t)(p ^ 1) * 65536 + hidx] = f2bf(h_);
            out[(size_t)t * 65536 + hidx] = h_;
            if (t == 511) {
                out[(size_t)512 * 65536 + hidx] = h_;              // Hf
                out[(size_t)512 * 65536 + 65536 + hidx] = c_state; // Cf
            }
        }

        // ---- per-batch-group barrier (64 WGs, monotonic counter) ----
        __syncthreads();
        if (tid == 0) {
            __threadfence();                     // release h stores device-wide
            atomicAdd(myctr, 1u);
            u32 tgt = (u32)(t + 1) * 64u;
            while (__hip_atomic_load(myctr, __ATOMIC_RELAXED, __HIP_MEMORY_SCOPE_AGENT) < tgt)
                __builtin_amdgcn_s_sleep(1);
        }
        __syncthreads();
        __threadfence();                         // acquire: invalidate stale h lines
    }
}

// ---------------------------------------------------------------------------
// Workspace layout (bytes):
//   xproj  @ 0          : 268,435,456  (bf16 [512*64][4096])
//   inb    @ 268435456  :  67,108,864  (bf16 inputs)
//   wxT    @ 335544320  :   8,388,608
//   whT    @ 343932928  :   8,388,608
//   bias   @ 352321536  :      16,384  (fp32 [4096])
//   hbuf   @ 352337920  :     262,144  (bf16 [2][64][1024])
//   ctr    @ 352600064  :       1,024
// total ~352.6 MB
// ---------------------------------------------------------------------------
extern "C" void kernel_launch(void* const* d_in, const int* in_sizes, int n_in,
                              void* d_out, int out_size, void* d_ws, size_t ws_size,
                              hipStream_t stream)
{
    const float* inputs = (const float*)d_in[0];
    const float* H0     = (const float*)d_in[1];
    const float* C0     = (const float*)d_in[2];
    const float* Wx[4]  = {(const float*)d_in[3], (const float*)d_in[6],
                           (const float*)d_in[9], (const float*)d_in[12]};
    const float* Wh[4]  = {(const float*)d_in[4], (const float*)d_in[7],
                           (const float*)d_in[10], (const float*)d_in[13]};
    const float* bs[4]  = {(const float*)d_in[5], (const float*)d_in[8],
                           (const float*)d_in[11], (const float*)d_in[14]};

    char* ws = (char*)d_ws;
    u16*  xproj = (u16*)(ws);
    u16*  inb   = (u16*)(ws + 268435456);
    u16*  wxT   = (u16*)(ws + 335544320);
    u16*  whT   = (u16*)(ws + 343932928);
    float* bias = (float*)(ws + 352321536);
    u16*  hbuf  = (u16*)(ws + 352337920);
    u32*  ctr   = (u32*)(ws + 352600064);
    float* out  = (float*)d_out;

    k_init<<<dim3(64), dim3(256), 0, stream>>>(H0, bs[0], bs[1], bs[2], bs[3], hbuf, bias, ctr);
    k_cvt<<<dim3(32768), dim3(256), 0, stream>>>((const float4*)inputs, (ushort4*)inb);
    k_wt<<<dim3(32, 32, 8), dim3(32, 8), 0, stream>>>(Wx[0], Wx[1], Wx[2], Wx[3],
                                                      Wh[0], Wh[1], Wh[2], Wh[3], wxT, whT);
    k_gemm<<<dim3(256, 32), dim3(256), 0, stream>>>(inb, wxT, xproj);
    k_scan<<<dim3(256), dim3(512), 0, stream>>>(xproj, whT, bias, C0, hbuf, ctr, out);
}

// Round 2
// 4622.466 us; speedup vs baseline: 4.7912x; 4.7912x over previous
//
#include <hip/hip_runtime.h>

// ============================================================================
// LSTM scan, T=512 B=64 D=H=1024.
//   K0 k_init : zero flags, bias concat, H0 -> bf16 hbuf[0]
//   K1 k_cvt  : inputs fp32 -> bf16
//   K2 k_wt   : 8x transpose+cvt weights -> WxT/WhT [4096][1024] bf16
//   K3 k_gemm : x_proj[32768][4096] = inputs @ Wx  (bf16 MFMA, 128x128x64)
//   K4 k_scan : persistent 256 WGs (4 batch-groups x 64 col-groups).
//               Cross-WG h exchange via relaxed AGENT-scope atomics (bypass
//               L1/L2, coherent at Infinity Cache) — NO threadfence / wbl2.
//               Per-wave ready flags + wave-parallel poll barrier.
//               Waves = 8 disjoint K-slices (128 each), all 4 gates per wave
//               (dedups h reads 4x); phased LDS reduction.
// ============================================================================

typedef unsigned short u16;
typedef unsigned int   u32;
typedef unsigned long long u64;
typedef __attribute__((ext_vector_type(8))) short bf16x8;   // 8 bf16 in 4 VGPRs
typedef __attribute__((ext_vector_type(4))) float f32x4;

__device__ __forceinline__ float bf2f(u16 u) {
    union { u32 i; float f; } v; v.i = ((u32)u) << 16; return v.f;
}
__device__ __forceinline__ u16 f2bf(float f) {   // round-to-nearest-even
    union { float f; u32 u; } v; v.f = f;
    u32 u = v.u;
    return (u16)((u + 0x7FFFu + ((u >> 16) & 1u)) >> 16);
}
__device__ __forceinline__ float sigm(float x)   { return 1.f / (1.f + __expf(-x)); }
__device__ __forceinline__ float tanh_f(float x) { return 1.f - 2.f / (1.f + __expf(2.f * x)); }

// ---------------------------------------------------------------------------
// K0: init — hbuf[0] = bf16(H0); bias concat [i|f|o|c]; zero flags.
// grid 64 x 256
// ---------------------------------------------------------------------------
__global__ void k_init(const float* __restrict__ H0,
                       const float* __restrict__ bi, const float* __restrict__ bff,
                       const float* __restrict__ bo, const float* __restrict__ bc,
                       u16* __restrict__ hbuf, float* __restrict__ bias,
                       u32* __restrict__ flags)
{
    int i = blockIdx.x * 256 + threadIdx.x;      // 0..16383
#pragma unroll
    for (int r = 0; r < 4; ++r) {
        int idx = i + r * 16384;                 // 0..65535
        hbuf[idx] = f2bf(H0[idx]);
    }
    if (i < 4096) {
        const float* bp = (i < 1024) ? bi : (i < 2048) ? bff : (i < 3072) ? bo : bc;
        bias[i] = bp[i & 1023];
    }
    if (i < 1024) flags[i] = 0u;                 // [4 bg][64 cg][4 wave]
}

// ---------------------------------------------------------------------------
// K1: inputs fp32 -> bf16 (33.5M elems). grid 32768 x 256, 4 elems/thread.
// ---------------------------------------------------------------------------
__global__ void k_cvt(const float4* __restrict__ in, ushort4* __restrict__ out)
{
    size_t i = (size_t)blockIdx.x * 256 + threadIdx.x;
    float4 v = in[i];
    ushort4 o;
    o.x = f2bf(v.x); o.y = f2bf(v.y); o.z = f2bf(v.z); o.w = f2bf(v.w);
    out[i] = o;
}

// ---------------------------------------------------------------------------
// K2: weight transpose+cvt.  src [1024][1024] fp32 row-major (k-major) ->
// dst [1024][1024] bf16 with rows = output cols.
// grid (32,32,8), block (32,8). z<4 -> WxT gate z ; z>=4 -> WhT gate z-4.
// ---------------------------------------------------------------------------
__global__ void k_wt(const float* s0, const float* s1, const float* s2, const float* s3,
                     const float* s4, const float* s5, const float* s6, const float* s7,
                     u16* __restrict__ wxT, u16* __restrict__ whT)
{
    const float* srcs[8] = {s0, s1, s2, s3, s4, s5, s6, s7};
    int z = blockIdx.z;
    const float* src = srcs[z];
    u16* dst = (z < 4) ? (wxT + (size_t)z * 1048576) : (whT + (size_t)(z - 4) * 1048576);
    __shared__ float tile[32][33];
    int k0 = blockIdx.x * 32, n0 = blockIdx.y * 32;
    int tx = threadIdx.x, ty = threadIdx.y;
#pragma unroll
    for (int s = 0; s < 4; ++s)
        tile[ty + 8 * s][tx] = src[(size_t)(k0 + ty + 8 * s) * 1024 + n0 + tx];
    __syncthreads();
#pragma unroll
    for (int s = 0; s < 4; ++s)
        dst[(size_t)(n0 + ty + 8 * s) * 1024 + k0 + tx] = f2bf(tile[tx][ty + 8 * s]);
}

// ---------------------------------------------------------------------------
// K3: x_proj GEMM.  C[32768][4096] bf16 = A[32768][1024] @ BT[4096][1024]^T.
// 128x128 tile, BK=64, 4 waves, mfma 16x16x32 bf16, XOR-swizzled LDS.
// grid (256, 32), block 256.
// ---------------------------------------------------------------------------
__global__ __launch_bounds__(256, 2) void k_gemm(const u16* __restrict__ A,
                                                 const u16* __restrict__ BT,
                                                 u16* __restrict__ C)
{
    __shared__ __attribute__((aligned(16))) u16 lsA[128][64];
    __shared__ __attribute__((aligned(16))) u16 lsB[128][64];
    const int tid  = threadIdx.x;
    const int lane = tid & 63;
    const int wv   = tid >> 6;
    const int wm   = wv >> 1, wn = wv & 1;
    const int m0   = blockIdx.x * 128;
    const int n0   = blockIdx.y * 128;
    const int fr   = lane & 15, fq = lane >> 4;
    const int srow = tid >> 3;
    const int sk8  = tid & 7;

    f32x4 acc[4][4] = {};

    for (int kt = 0; kt < 16; ++kt) {
        const int k0 = kt * 64;
#pragma unroll
        for (int it = 0; it < 4; ++it) {
            int row = srow + it * 32;
            int kg  = (sk8 ^ (row & 7)) * 8;
            uint4 va = *(const uint4*)(A  + (size_t)(m0 + row) * 1024 + k0 + kg);
            uint4 vb = *(const uint4*)(BT + (size_t)(n0 + row) * 1024 + k0 + kg);
            *(uint4*)&lsA[row][sk8 * 8] = va;
            *(uint4*)&lsB[row][sk8 * 8] = vb;
        }
        __syncthreads();
#pragma unroll
        for (int kc = 0; kc < 2; ++kc) {
            const int kb = kc * 32 + 8 * fq;
            bf16x8 af[4], bfv[4];
#pragma unroll
            for (int i = 0; i < 4; ++i) {
                int ra = 64 * wm + 16 * i + fr;
                af[i] = *(const bf16x8*)&lsA[ra][kb ^ ((ra & 7) * 8)];
            }
#pragma unroll
            for (int j = 0; j < 4; ++j) {
                int rb = 64 * wn + 16 * j + fr;
                bfv[j] = *(const bf16x8*)&lsB[rb][kb ^ ((rb & 7) * 8)];
            }
#pragma unroll
            for (int i = 0; i < 4; ++i)
#pragma unroll
                for (int j = 0; j < 4; ++j)
                    acc[i][j] = __builtin_amdgcn_mfma_f32_16x16x32_bf16(af[i], bfv[j], acc[i][j], 0, 0, 0);
        }
        __syncthreads();
    }
#pragma unroll
    for (int i = 0; i < 4; ++i) {
        int grow = m0 + 64 * wm + 16 * i + 4 * fq;
#pragma unroll
        for (int j = 0; j < 4; ++j) {
            int gcol = n0 + 64 * wn + 16 * j + fr;
#pragma unroll
            for (int r = 0; r < 4; ++r)
                C[(size_t)(grow + r) * 4096 + gcol] = f2bf(acc[i][j][r]);
        }
    }
}

// ---------------------------------------------------------------------------
// K4: persistent LSTM scan.
// 256 WGs x 512 thr.  WG = (bg 0..3, cg 0..63): batches bg*16..+15, h-cols cg*16..+15.
// LDS: Wh slice [64 gate-rows][1024] bf16 swizzled (128KB) + partials (16KB)
//  -> 1 WG/CU, grid == 256 CUs, spin barrier safe.
// Waves = 8 K-slices of 128; each computes all 4 gates (h reads dedup'd).
// All cross-WG traffic via relaxed agent-scope atomics (L2-bypass, coherent).
// ---------------------------------------------------------------------------
__global__ __launch_bounds__(512, 1) void k_scan(const u16* __restrict__ xproj,  // [512][64][4096]
                                                 const u16* __restrict__ whT,    // [4096][1024]
                                                 const float* __restrict__ bias, // [4096]
                                                 const float* __restrict__ C0,   // [64][1024]
                                                 u16* __restrict__ hbuf,         // [2][64][1024]
                                                 u32* __restrict__ flags,        // [4][64][4]
                                                 float* __restrict__ out)        // outputs|Hf|Cf
{
    __shared__ __attribute__((aligned(16))) u16   lds_w[64][1024];    // 128 KB
    __shared__ __attribute__((aligned(16))) float lds_p[4][4][16][16]; // 16 KB

    const int wg  = blockIdx.x;
    const int bg  = wg >> 6;          // batch group 0..3
    const int cg  = wg & 63;          // col group   0..63
    const int b0  = bg * 16;
    const int j0  = cg * 16;
    const int tid = threadIdx.x;
    const int lane = tid & 63;
    const int wv  = tid >> 6;         // 0..7 = K-slice
    const int fr  = lane & 15;
    const int fq  = lane >> 4;

    // ---- load Wh slice into LDS, swizzled: elem (n,k) at [n][k ^ ((n&7)*8)] ----
    for (int it = 0; it < 16; ++it) {
        int idx = tid + it * 512;               // uint4 index, 8192 total
        int row = idx >> 7;                     // 0..63   (gate*16 + jj)
        int k8  = idx & 127;
        int gg  = row >> 4, jj = row & 15;
        uint4 v = *((const uint4*)(whT + ((size_t)(gg * 1024 + j0 + jj) << 10)) + k8);
        *(uint4*)&lds_w[row][(k8 * 8) ^ ((row & 7) * 8)] = v;
    }

    // ---- per-thread recurrent state (threads 0..255) ----
    const int eb = tid >> 4;   // local batch 0..15
    const int ej = tid & 15;   // local h-col 0..15
    float c_state = 0.f;
    float bia[4] = {0.f, 0.f, 0.f, 0.f};
    if (tid < 256) {
        c_state = C0[(size_t)(b0 + eb) * 1024 + j0 + ej];
#pragma unroll
        for (int q = 0; q < 4; ++q) bia[q] = bias[q * 1024 + j0 + ej];
    }
    __syncthreads();

    const int ks = wv;                            // K-slice: cols ks*128..+127
    u32* fl = flags + bg * 256;                   // this group's flag block

    for (int t = 0; t < 512; ++t) {
        const int p = t & 1;
        const u16* hb = hbuf + (size_t)p * 65536;

        // ---- A-frags: coherent (agent-scope) h loads, 8 x 8B per lane ----
        union { bf16x8 v[4]; u64 q[8]; } afu;
        {
            const u64* hp = (const u64*)(hb + (size_t)(b0 + fr) * 1024 + ks * 128 + 8 * fq);
#pragma unroll
            for (int kk = 0; kk < 4; ++kk) {
                afu.q[kk * 2 + 0] = __hip_atomic_load(hp + kk * 8 + 0, __ATOMIC_RELAXED, __HIP_MEMORY_SCOPE_AGENT);
                afu.q[kk * 2 + 1] = __hip_atomic_load(hp + kk * 8 + 1, __ATOMIC_RELAXED, __HIP_MEMORY_SCOPE_AGENT);
            }
        }

        // ---- xg prefetch (normal cached loads; xproj is read-only) ----
        float xg[4] = {0.f, 0.f, 0.f, 0.f};
        if (tid < 256) {
            const u16* xp = xproj + ((size_t)t * 64 + (b0 + eb)) * 4096 + j0 + ej;
#pragma unroll
            for (int q = 0; q < 4; ++q) xg[q] = bf2f(xp[q * 1024]);
        }

        // ---- MFMA: 4 gates x 4 k-chunks on this wave's K-slice ----
        f32x4 acc[4] = {};
#pragma unroll
        for (int g = 0; g < 4; ++g) {
            const int row = g * 16 + fr;
            const int swz = (row & 7) * 8;
#pragma unroll
            for (int kk = 0; kk < 4; ++kk) {
                bf16x8 bv = *(const bf16x8*)&lds_w[row][(ks * 128 + kk * 32 + 8 * fq) ^ swz];
                acc[g] = __builtin_amdgcn_mfma_f32_16x16x32_bf16(afu.v[kk], bv, acc[g], 0, 0, 0);
            }
        }

        // ---- phased cross-wave reduction (C layout: row=4*fq+r, col=fr) ----
        if (wv >= 4) {
#pragma unroll
            for (int g = 0; g < 4; ++g)
#pragma unroll
                for (int r = 0; r < 4; ++r)
                    lds_p[wv - 4][g][4 * fq + r][fr] = acc[g][r];
        }
        __syncthreads();
        if (wv < 4) {
#pragma unroll
            for (int g = 0; g < 4; ++g)
#pragma unroll
                for (int r = 0; r < 4; ++r)
                    lds_p[wv][g][4 * fq + r][fr] += acc[g][r];
        }
        __syncthreads();

        // ---- elementwise LSTM cell (threads 0..255) + publish ----
        if (tid < 256) {
            float gate[4];
#pragma unroll
            for (int q = 0; q < 4; ++q)
                gate[q] = lds_p[0][q][eb][ej] + lds_p[1][q][eb][ej]
                        + lds_p[2][q][eb][ej] + lds_p[3][q][eb][ej] + xg[q] + bia[q];
            float i_ = sigm(gate[0]);
            float f_ = sigm(gate[1]);
            float o_ = sigm(gate[2]);
            float g_ = tanh_f(gate[3]);
            c_state = f_ * c_state + i_ * g_;
            float h_ = o_ * tanh_f(c_state);

            size_t hidx = (size_t)(b0 + eb) * 1024 + j0 + ej;
            out[(size_t)t * 65536 + hidx] = h_;
            if (t == 511) {
                out[(size_t)33554432 + hidx] = h_;              // Hf
                out[(size_t)33554432 + 65536 + hidx] = c_state; // Cf
            }
            // h -> coherent buffer (pack 2 bf16 per u32 via shfl)
            float hn = __shfl_down(h_, 1);
            if ((ej & 1) == 0) {
                u32 hv = (u32)f2bf(h_) | ((u32)f2bf(hn) << 16);
                __hip_atomic_store((u32*)(hbuf + (size_t)(p ^ 1) * 65536 + hidx), hv,
                                   __ATOMIC_RELAXED, __HIP_MEMORY_SCOPE_AGENT);
            }
            // drain this wave's stores to the coherence point, then publish flag
            asm volatile("s_waitcnt vmcnt(0)" ::: "memory");
            if (lane == 0)
                __hip_atomic_store(fl + cg * 4 + wv, (u32)(t + 1),
                                   __ATOMIC_RELAXED, __HIP_MEMORY_SCOPE_AGENT);
        }

        // ---- wave 4: wave-parallel poll of 64 cg x 4 wave flags ----
        if (wv == 4) {
            const u64* fp = (const u64*)(fl + lane * 4);
            const u32 tgt = (u32)(t + 1);
            while (true) {
                u64 a = __hip_atomic_load(fp + 0, __ATOMIC_RELAXED, __HIP_MEMORY_SCOPE_AGENT);
                u64 b = __hip_atomic_load(fp + 1, __ATOMIC_RELAXED, __HIP_MEMORY_SCOPE_AGENT);
                bool ok = ((u32)a >= tgt) && ((u32)(a >> 32) >= tgt) &&
                          ((u32)b >= tgt) && ((u32)(b >> 32) >= tgt);
                if (__all(ok)) break;
            }
        }
        __syncthreads();
    }
}

// ---------------------------------------------------------------------------
// Workspace layout (bytes):
//   xproj  @ 0          : 268,435,456  (bf16 [512*64][4096])
//   inb    @ 268435456  :  67,108,864  (bf16 inputs)
//   wxT    @ 335544320  :   8,388,608
//   whT    @ 343932928  :   8,388,608
//   bias   @ 352321536  :      16,384  (fp32 [4096])
//   hbuf   @ 352337920  :     262,144  (bf16 [2][64][1024])
//   flags  @ 352600064  :       4,096
// ---------------------------------------------------------------------------
extern "C" void kernel_launch(void* const* d_in, const int* in_sizes, int n_in,
                              void* d_out, int out_size, void* d_ws, size_t ws_size,
                              hipStream_t stream)
{
    const float* inputs = (const float*)d_in[0];
    const float* H0     = (const float*)d_in[1];
    const float* C0     = (const float*)d_in[2];
    const float* Wx[4]  = {(const float*)d_in[3], (const float*)d_in[6],
                           (const float*)d_in[9], (const float*)d_in[12]};
    const float* Wh[4]  = {(const float*)d_in[4], (const float*)d_in[7],
                           (const float*)d_in[10], (const float*)d_in[13]};
    const float* bs[4]  = {(const float*)d_in[5], (const float*)d_in[8],
                           (const float*)d_in[11], (const float*)d_in[14]};

    char* ws = (char*)d_ws;
    u16*  xproj = (u16*)(ws);
    u16*  inb   = (u16*)(ws + 268435456);
    u16*  wxT   = (u16*)(ws + 335544320);
    u16*  whT   = (u16*)(ws + 343932928);
    float* bias = (float*)(ws + 352321536);
    u16*  hbuf  = (u16*)(ws + 352337920);
    u32*  flags = (u32*)(ws + 352600064);
    float* out  = (float*)d_out;

    k_init<<<dim3(64), dim3(256), 0, stream>>>(H0, bs[0], bs[1], bs[2], bs[3], hbuf, bias, flags);
    k_cvt<<<dim3(32768), dim3(256), 0, stream>>>((const float4*)inputs, (ushort4*)inb);
    k_wt<<<dim3(32, 32, 8), dim3(32, 8), 0, stream>>>(Wx[0], Wx[1], Wx[2], Wx[3],
                                                      Wh[0], Wh[1], Wh[2], Wh[3], wxT, whT);
    k_gemm<<<dim3(256, 32), dim3(256), 0, stream>>>(inb, wxT, xproj);
    k_scan<<<dim3(256), dim3(512), 0, stream>>>(xproj, whT, bias, C0, hbuf, flags, out);
}

// Round 5
// 3974.712 us; speedup vs baseline: 5.5721x; 1.1630x over previous
//
#include <hip/hip_runtime.h>

// ============================================================================
// LSTM scan, T=512 B=64 D=H=1024.
//   K0 k_init : zero flags, bias concat, H0 -> bf16 hbuf[0]
//   K1 k_cvt  : inputs fp32 -> bf16
//   K2 k_wt   : 8x transpose+cvt weights -> WxT/WhT [4096][1024] bf16
//   K3 k_gemm : x_proj[32768][4096] = inputs @ Wx  (bf16 MFMA, 128x128x64)
//   K4 k_scan : persistent 256 WGs (4 batch-groups x 64 col-groups).
//               h exchange: producers write-through to L3 (agent-scope relaxed
//               stores), consumers read with NORMAL CACHED loads after a
//               per-step acquire fence (buffer_inv, no writeback) -> each XCD
//               fetches each h line once, L2 serves the broadcast.
//               Per-wave ready flags (uncached) + wave-parallel poll barrier.
// ============================================================================

typedef unsigned short u16;
typedef unsigned int   u32;
typedef unsigned long long u64;
typedef __attribute__((ext_vector_type(8))) short bf16x8;   // 8 bf16 in 4 VGPRs
typedef __attribute__((ext_vector_type(4))) float f32x4;

__device__ __forceinline__ float bf2f(u16 u) {
    union { u32 i; float f; } v; v.i = ((u32)u) << 16; return v.f;
}
__device__ __forceinline__ u16 f2bf(float f) {   // round-to-nearest-even
    union { float f; u32 u; } v; v.f = f;
    u32 u = v.u;
    return (u16)((u + 0x7FFFu + ((u >> 16) & 1u)) >> 16);
}
__device__ __forceinline__ float sigm(float x)   { return 1.f / (1.f + __expf(-x)); }
__device__ __forceinline__ float tanh_f(float x) { return 1.f - 2.f / (1.f + __expf(2.f * x)); }

// ---------------------------------------------------------------------------
// K0: init — hbuf[0] = bf16(H0); bias concat [i|f|o|c]; zero flags.
// grid 64 x 256
// ---------------------------------------------------------------------------
__global__ void k_init(const float* __restrict__ H0,
                       const float* __restrict__ bi, const float* __restrict__ bff,
                       const float* __restrict__ bo, const float* __restrict__ bc,
                       u16* __restrict__ hbuf, float* __restrict__ bias,
                       u32* __restrict__ flags)
{
    int i = blockIdx.x * 256 + threadIdx.x;      // 0..16383
#pragma unroll
    for (int r = 0; r < 4; ++r) {
        int idx = i + r * 16384;                 // 0..65535
        hbuf[idx] = f2bf(H0[idx]);
    }
    if (i < 4096) {
        const float* bp = (i < 1024) ? bi : (i < 2048) ? bff : (i < 3072) ? bo : bc;
        bias[i] = bp[i & 1023];
    }
    if (i < 1024) flags[i] = 0u;                 // [4 bg][64 cg][4 wave]
}

// ---------------------------------------------------------------------------
// K1: inputs fp32 -> bf16 (33.5M elems). grid 32768 x 256, 4 elems/thread.
// ---------------------------------------------------------------------------
__global__ void k_cvt(const float4* __restrict__ in, ushort4* __restrict__ out)
{
    size_t i = (size_t)blockIdx.x * 256 + threadIdx.x;
    float4 v = in[i];
    ushort4 o;
    o.x = f2bf(v.x); o.y = f2bf(v.y); o.z = f2bf(v.z); o.w = f2bf(v.w);
    out[i] = o;
}

// ---------------------------------------------------------------------------
// K2: weight transpose+cvt.  src [1024][1024] fp32 row-major (k-major) ->
// dst [1024][1024] bf16 with rows = output cols.
// grid (32,32,8), block (32,8). z<4 -> WxT gate z ; z>=4 -> WhT gate z-4.
// ---------------------------------------------------------------------------
__global__ void k_wt(const float* s0, const float* s1, const float* s2, const float* s3,
                     const float* s4, const float* s5, const float* s6, const float* s7,
                     u16* __restrict__ wxT, u16* __restrict__ whT)
{
    const float* srcs[8] = {s0, s1, s2, s3, s4, s5, s6, s7};
    int z = blockIdx.z;
    const float* src = srcs[z];
    u16* dst = (z < 4) ? (wxT + (size_t)z * 1048576) : (whT + (size_t)(z - 4) * 1048576);
    __shared__ float tile[32][33];
    int k0 = blockIdx.x * 32, n0 = blockIdx.y * 32;
    int tx = threadIdx.x, ty = threadIdx.y;
#pragma unroll
    for (int s = 0; s < 4; ++s)
        tile[ty + 8 * s][tx] = src[(size_t)(k0 + ty + 8 * s) * 1024 + n0 + tx];
    __syncthreads();
#pragma unroll
    for (int s = 0; s < 4; ++s)
        dst[(size_t)(n0 + ty + 8 * s) * 1024 + k0 + tx] = f2bf(tile[tx][ty + 8 * s]);
}

// ---------------------------------------------------------------------------
// K3: x_proj GEMM.  C[32768][4096] bf16 = A[32768][1024] @ BT[4096][1024]^T.
// 128x128 tile, BK=64, 4 waves, mfma 16x16x32 bf16, XOR-swizzled LDS.
// grid (256, 32), block 256.
// ---------------------------------------------------------------------------
__global__ __launch_bounds__(256, 2) void k_gemm(const u16* __restrict__ A,
                                                 const u16* __restrict__ BT,
                                                 u16* __restrict__ C)
{
    __shared__ __attribute__((aligned(16))) u16 lsA[128][64];
    __shared__ __attribute__((aligned(16))) u16 lsB[128][64];
    const int tid  = threadIdx.x;
    const int lane = tid & 63;
    const int wv   = tid >> 6;
    const int wm   = wv >> 1, wn = wv & 1;
    const int m0   = blockIdx.x * 128;
    const int n0   = blockIdx.y * 128;
    const int fr   = lane & 15, fq = lane >> 4;
    const int srow = tid >> 3;
    const int sk8  = tid & 7;

    f32x4 acc[4][4] = {};

    for (int kt = 0; kt < 16; ++kt) {
        const int k0 = kt * 64;
#pragma unroll
        for (int it = 0; it < 4; ++it) {
            int row = srow + it * 32;
            int kg  = (sk8 ^ (row & 7)) * 8;
            uint4 va = *(const uint4*)(A  + (size_t)(m0 + row) * 1024 + k0 + kg);
            uint4 vb = *(const uint4*)(BT + (size_t)(n0 + row) * 1024 + k0 + kg);
            *(uint4*)&lsA[row][sk8 * 8] = va;
            *(uint4*)&lsB[row][sk8 * 8] = vb;
        }
        __syncthreads();
#pragma unroll
        for (int kc = 0; kc < 2; ++kc) {
            const int kb = kc * 32 + 8 * fq;
            bf16x8 af[4], bfv[4];
#pragma unroll
            for (int i = 0; i < 4; ++i) {
                int ra = 64 * wm + 16 * i + fr;
                af[i] = *(const bf16x8*)&lsA[ra][kb ^ ((ra & 7) * 8)];
            }
#pragma unroll
            for (int j = 0; j < 4; ++j) {
                int rb = 64 * wn + 16 * j + fr;
                bfv[j] = *(const bf16x8*)&lsB[rb][kb ^ ((rb & 7) * 8)];
            }
#pragma unroll
            for (int i = 0; i < 4; ++i)
#pragma unroll
                for (int j = 0; j < 4; ++j)
                    acc[i][j] = __builtin_amdgcn_mfma_f32_16x16x32_bf16(af[i], bfv[j], acc[i][j], 0, 0, 0);
        }
        __syncthreads();
    }
#pragma unroll
    for (int i = 0; i < 4; ++i) {
        int grow = m0 + 64 * wm + 16 * i + 4 * fq;
#pragma unroll
        for (int j = 0; j < 4; ++j) {
            int gcol = n0 + 64 * wn + 16 * j + fr;
#pragma unroll
            for (int r = 0; r < 4; ++r)
                C[(size_t)(grow + r) * 4096 + gcol] = f2bf(acc[i][j][r]);
        }
    }
}

// ---------------------------------------------------------------------------
// K4: persistent LSTM scan.
// 256 WGs x 512 thr.  WG = (bg 0..3, cg 0..63): batches bg*16..+15, h-cols cg*16..+15.
// LDS: Wh slice [64 gate-rows][1024] bf16 swizzled (128KB) + partials (16KB)
//  -> 1 WG/CU, grid == 256 CUs, spin barrier safe.
// Waves = 8 K-slices of 128; each computes all 4 gates.
// h: producer agent-store (write-through L3), consumer CACHED loads after a
// per-step acquire fence (buffer_inv) -> L2 serves the 64-way broadcast.
// Flags stay uncached agent-scope.
// ---------------------------------------------------------------------------
__global__ __launch_bounds__(512, 1) void k_scan(const u16* __restrict__ xproj,  // [512][64][4096]
                                                 const u16* __restrict__ whT,    // [4096][1024]
                                                 const float* __restrict__ bias, // [4096]
                                                 const float* __restrict__ C0,   // [64][1024]
                                                 u16* __restrict__ hbuf,         // [2][64][1024]
                                                 u32* __restrict__ flags,        // [4][64][4]
                                                 float* __restrict__ out)        // outputs|Hf|Cf
{
    __shared__ __attribute__((aligned(16))) u16   lds_w[64][1024];    // 128 KB
    __shared__ __attribute__((aligned(16))) float lds_p[4][4][16][16]; // 16 KB

    const int wg  = blockIdx.x;
    const int bg  = wg >> 6;          // batch group 0..3
    const int cg  = wg & 63;          // col group   0..63
    const int b0  = bg * 16;
    const int j0  = cg * 16;
    const int tid = threadIdx.x;
    const int lane = tid & 63;
    const int wv  = tid >> 6;         // 0..7 = K-slice
    const int fr  = lane & 15;
    const int fq  = lane >> 4;

    // ---- load Wh slice into LDS, swizzled: elem (n,k) at [n][k ^ ((n&7)*8)] ----
    for (int it = 0; it < 16; ++it) {
        int idx = tid + it * 512;               // uint4 index, 8192 total
        int row = idx >> 7;                     // 0..63   (gate*16 + jj)
        int k8  = idx & 127;
        int gg  = row >> 4, jj = row & 15;
        uint4 v = *((const uint4*)(whT + ((size_t)(gg * 1024 + j0 + jj) << 10)) + k8);
        *(uint4*)&lds_w[row][(k8 * 8) ^ ((row & 7) * 8)] = v;
    }

    // ---- per-thread recurrent state (threads 0..255) ----
    const int eb = tid >> 4;   // local batch 0..15
    const int ej = tid & 15;   // local h-col 0..15
    float c_state = 0.f;
    float bia[4] = {0.f, 0.f, 0.f, 0.f};
    if (tid < 256) {
        c_state = C0[(size_t)(b0 + eb) * 1024 + j0 + ej];
#pragma unroll
        for (int q = 0; q < 4; ++q) bia[q] = bias[q * 1024 + j0 + ej];
    }
    __syncthreads();

    const int ks = wv;                            // K-slice: cols ks*128..+127
    u32* fl = flags + bg * 256;                   // this group's flag block

    for (int t = 0; t < 512; ++t) {
        const int p = t & 1;
        const u16* hb = hbuf + (size_t)p * 65536;

        // ---- A-frags: CACHED coalesced h loads (L2 serves the broadcast) ----
        union { bf16x8 v[4]; uint4 q[4]; } afu;
        {
            const u16* hp = hb + (size_t)(b0 + fr) * 1024 + ks * 128 + 8 * fq;
#pragma unroll
            for (int kk = 0; kk < 4; ++kk)
                afu.q[kk] = *(const uint4*)(hp + kk * 32);
        }

        // ---- xg prefetch (cached; consumed at elementwise) ----
        float xg[4] = {0.f, 0.f, 0.f, 0.f};
        if (tid < 256) {
            const u16* xp = xproj + ((size_t)t * 64 + (b0 + eb)) * 4096 + j0 + ej;
#pragma unroll
            for (int q = 0; q < 4; ++q) xg[q] = bf2f(xp[q * 1024]);
        }

        // ---- MFMA: 4 gates x 4 k-chunks on this wave's K-slice ----
        f32x4 acc[4] = {};
#pragma unroll
        for (int g = 0; g < 4; ++g) {
            const int row = g * 16 + fr;
            const int swz = (row & 7) * 8;
#pragma unroll
            for (int kk = 0; kk < 4; ++kk) {
                bf16x8 bv = *(const bf16x8*)&lds_w[row][(ks * 128 + kk * 32 + 8 * fq) ^ swz];
                acc[g] = __builtin_amdgcn_mfma_f32_16x16x32_bf16(afu.v[kk], bv, acc[g], 0, 0, 0);
            }
        }

        // ---- phased cross-wave reduction (C layout: row=4*fq+r, col=fr) ----
        if (wv >= 4) {
#pragma unroll
            for (int g = 0; g < 4; ++g)
#pragma unroll
                for (int r = 0; r < 4; ++r)
                    lds_p[wv - 4][g][4 * fq + r][fr] = acc[g][r];
        }
        __syncthreads();
        if (wv < 4) {
#pragma unroll
            for (int g = 0; g < 4; ++g)
#pragma unroll
                for (int r = 0; r < 4; ++r)
                    lds_p[wv][g][4 * fq + r][fr] += acc[g][r];
        }
        __syncthreads();

        // ---- elementwise LSTM cell (threads 0..255) + publish ----
        if (tid < 256) {
            float gate[4];
#pragma unroll
            for (int q = 0; q < 4; ++q)
                gate[q] = lds_p[0][q][eb][ej] + lds_p[1][q][eb][ej]
                        + lds_p[2][q][eb][ej] + lds_p[3][q][eb][ej] + xg[q] + bia[q];
            float i_ = sigm(gate[0]);
            float f_ = sigm(gate[1]);
            float o_ = sigm(gate[2]);
            float g_ = tanh_f(gate[3]);
            c_state = f_ * c_state + i_ * g_;
            float h_ = o_ * tanh_f(c_state);

            size_t hidx = (size_t)(b0 + eb) * 1024 + j0 + ej;

            // h -> write-through coherent buffer, packed 8B per 4 lanes
            u32 lo = (u32)f2bf(h_) | ((u32)f2bf(__shfl_down(h_, 1)) << 16);     // even ej
            u64 qv = (u64)lo | ((u64)(u32)__shfl_down((int)lo, 2) << 32);       // ej%4==0
            if ((ej & 3) == 0)
                __hip_atomic_store((u64*)(hbuf + (size_t)(p ^ 1) * 65536 + hidx), qv,
                                   __ATOMIC_RELAXED, __HIP_MEMORY_SCOPE_AGENT);
            // drain this wave's h stores to the coherence point, then publish flag
            asm volatile("s_waitcnt vmcnt(0)" ::: "memory");
            if (lane == 0)
                __hip_atomic_store(fl + cg * 4 + wv, (u32)(t + 1),
                                   __ATOMIC_RELAXED, __HIP_MEMORY_SCOPE_AGENT);

            // out stores AFTER flag publish (off the critical path)
            out[(size_t)t * 65536 + hidx] = h_;
            if (t == 511) {
                out[(size_t)33554432 + hidx] = h_;              // Hf
                out[(size_t)33554432 + 65536 + hidx] = c_state; // Cf
            }
        }

        // ---- wave 4: wave-parallel poll of 64 cg x 4 wave flags, then acquire ----
        if (wv == 4) {
            const u64* fp = (const u64*)(fl + lane * 4);
            const u32 tgt = (u32)(t + 1);
            while (true) {
                u64 a = __hip_atomic_load(fp + 0, __ATOMIC_RELAXED, __HIP_MEMORY_SCOPE_AGENT);
                u64 b = __hip_atomic_load(fp + 1, __ATOMIC_RELAXED, __HIP_MEMORY_SCOPE_AGENT);
                bool ok = ((u32)a >= tgt) && ((u32)(a >> 32) >= tgt) &&
                          ((u32)b >= tgt) && ((u32)(b >> 32) >= tgt);
                if (__all(ok)) break;
            }
            // acquire: invalidate stale L1/L2 lines (no writeback) so next
            // step's cached h loads see the write-through data.
            __builtin_amdgcn_fence(__ATOMIC_ACQUIRE, "agent");
        }
        __syncthreads();
    }
}

// ---------------------------------------------------------------------------
// Workspace layout (bytes):
//   xproj  @ 0          : 268,435,456  (bf16 [512*64][4096])
//   inb    @ 268435456  :  67,108,864  (bf16 inputs)
//   wxT    @ 335544320  :   8,388,608
//   whT    @ 343932928  :   8,388,608
//   bias   @ 352321536  :      16,384  (fp32 [4096])
//   hbuf   @ 352337920  :     262,144  (bf16 [2][64][1024])
//   flags  @ 352600064  :       4,096
// ---------------------------------------------------------------------------
extern "C" void kernel_launch(void* const* d_in, const int* in_sizes, int n_in,
                              void* d_out, int out_size, void* d_ws, size_t ws_size,
                              hipStream_t stream)
{
    const float* inputs = (const float*)d_in[0];
    const float* H0     = (const float*)d_in[1];
    const float* C0     = (const float*)d_in[2];
    const float* Wx[4]  = {(const float*)d_in[3], (const float*)d_in[6],
                           (const float*)d_in[9], (const float*)d_in[12]};
    const float* Wh[4]  = {(const float*)d_in[4], (const float*)d_in[7],
                           (const float*)d_in[10], (const float*)d_in[13]};
    const float* bs[4]  = {(const float*)d_in[5], (const float*)d_in[8],
                           (const float*)d_in[11], (const float*)d_in[14]};

    char* ws = (char*)d_ws;
    u16*  xproj = (u16*)(ws);
    u16*  inb   = (u16*)(ws + 268435456);
    u16*  wxT   = (u16*)(ws + 335544320);
    u16*  whT   = (u16*)(ws + 343932928);
    float* bias = (float*)(ws + 352321536);
    u16*  hbuf  = (u16*)(ws + 352337920);
    u32*  flags = (u32*)(ws + 352600064);
    float* out  = (float*)d_out;

    k_init<<<dim3(64), dim3(256), 0, stream>>>(H0, bs[0], bs[1], bs[2], bs[3], hbuf, bias, flags);
    k_cvt<<<dim3(32768), dim3(256), 0, stream>>>((const float4*)inputs, (ushort4*)inb);
    k_wt<<<dim3(32, 32, 8), dim3(32, 8), 0, stream>>>(Wx[0], Wx[1], Wx[2], Wx[3],
                                                      Wh[0], Wh[1], Wh[2], Wh[3], wxT, whT);
    k_gemm<<<dim3(256, 32), dim3(256), 0, stream>>>(inb, wxT, xproj);
    k_scan<<<dim3(256), dim3(512), 0, stream>>>(xproj, whT, bias, C0, hbuf, flags, out);
}

// Round 6
// 3725.327 us; speedup vs baseline: 5.9451x; 1.0669x over previous
//
#include <hip/hip_runtime.h>

// ============================================================================
// LSTM scan, T=512 B=64 D=H=1024.
//   K0 k_init : zero counters, bias concat, H0 -> bf16 hbuf[0]
//   K1 k_cvt  : inputs fp32 -> bf16
//   K2 k_wt   : 8x transpose+cvt weights -> WxT/WhT [4096][1024] bf16
//   K3 k_gemm : x_proj = inputs @ Wx (bf16 MFMA, 128x128x64), epilogue writes
//               scan-friendly layout xproj[t][bg][cg][q][eb][ej] (2KB/WG/step)
//   K4 k_scan : persistent 256 WGs (4 batch-groups x 64 col-groups).
//               h: producer agent-store write-through, consumer CACHED loads
//               after per-step acquire fence (inv only) -> L2 serves broadcast.
//               Sync: per-bg epoch counter (1 atomicAdd/WG/step) + 1-lane poll
//               (replaces 256-flag wave-poll that congested the MALL).
// ============================================================================

typedef unsigned short u16;
typedef unsigned int   u32;
typedef unsigned long long u64;
typedef __attribute__((ext_vector_type(8))) short bf16x8;   // 8 bf16 in 4 VGPRs
typedef __attribute__((ext_vector_type(4))) float f32x4;

__device__ __forceinline__ float bf2f(u16 u) {
    union { u32 i; float f; } v; v.i = ((u32)u) << 16; return v.f;
}
__device__ __forceinline__ u16 f2bf(float f) {   // round-to-nearest-even
    union { float f; u32 u; } v; v.f = f;
    u32 u = v.u;
    return (u16)((u + 0x7FFFu + ((u >> 16) & 1u)) >> 16);
}
__device__ __forceinline__ float sigm(float x)   { return 1.f / (1.f + __expf(-x)); }
__device__ __forceinline__ float tanh_f(float x) { return 1.f - 2.f / (1.f + __expf(2.f * x)); }

// ---------------------------------------------------------------------------
// K0: init — hbuf[0] = bf16(H0); bias concat [i|f|o|c]; zero counters.
// grid 64 x 256
// ---------------------------------------------------------------------------
__global__ void k_init(const float* __restrict__ H0,
                       const float* __restrict__ bi, const float* __restrict__ bff,
                       const float* __restrict__ bo, const float* __restrict__ bc,
                       u16* __restrict__ hbuf, float* __restrict__ bias,
                       u32* __restrict__ ctr)
{
    int i = blockIdx.x * 256 + threadIdx.x;      // 0..16383
#pragma unroll
    for (int r = 0; r < 4; ++r) {
        int idx = i + r * 16384;                 // 0..65535
        hbuf[idx] = f2bf(H0[idx]);
    }
    if (i < 4096) {
        const float* bp = (i < 1024) ? bi : (i < 2048) ? bff : (i < 3072) ? bo : bc;
        bias[i] = bp[i & 1023];
    }
    if (i < 1024) ctr[i] = 0u;                   // bg counters at ctr[bg*64]
}

// ---------------------------------------------------------------------------
// K1: inputs fp32 -> bf16 (33.5M elems). grid 32768 x 256, 4 elems/thread.
// ---------------------------------------------------------------------------
__global__ void k_cvt(const float4* __restrict__ in, ushort4* __restrict__ out)
{
    size_t i = (size_t)blockIdx.x * 256 + threadIdx.x;
    float4 v = in[i];
    ushort4 o;
    o.x = f2bf(v.x); o.y = f2bf(v.y); o.z = f2bf(v.z); o.w = f2bf(v.w);
    out[i] = o;
}

// ---------------------------------------------------------------------------
// K2: weight transpose+cvt.  src [1024][1024] fp32 row-major (k-major) ->
// dst [1024][1024] bf16 with rows = output cols.
// grid (32,32,8), block (32,8). z<4 -> WxT gate z ; z>=4 -> WhT gate z-4.
// ---------------------------------------------------------------------------
__global__ void k_wt(const float* s0, const float* s1, const float* s2, const float* s3,
                     const float* s4, const float* s5, const float* s6, const float* s7,
                     u16* __restrict__ wxT, u16* __restrict__ whT)
{
    const float* srcs[8] = {s0, s1, s2, s3, s4, s5, s6, s7};
    int z = blockIdx.z;
    const float* src = srcs[z];
    u16* dst = (z < 4) ? (wxT + (size_t)z * 1048576) : (whT + (size_t)(z - 4) * 1048576);
    __shared__ float tile[32][33];
    int k0 = blockIdx.x * 32, n0 = blockIdx.y * 32;
    int tx = threadIdx.x, ty = threadIdx.y;
#pragma unroll
    for (int s = 0; s < 4; ++s)
        tile[ty + 8 * s][tx] = src[(size_t)(k0 + ty + 8 * s) * 1024 + n0 + tx];
    __syncthreads();
#pragma unroll
    for (int s = 0; s < 4; ++s)
        dst[(size_t)(n0 + ty + 8 * s) * 1024 + k0 + tx] = f2bf(tile[tx][ty + 8 * s]);
}

// ---------------------------------------------------------------------------
// K3: x_proj GEMM.  [32768][1024] @ [4096][1024]^T, bf16 MFMA 128x128x64.
// Epilogue writes xproj[t][bg][cg][q][eb][ej]: per (t, scan-WG) slice is one
// contiguous 2KB block -> full-line HBM fetches in the scan, no over-fetch.
// grid (256, 32), block 256.
// ---------------------------------------------------------------------------
__global__ __launch_bounds__(256, 2) void k_gemm(const u16* __restrict__ A,
                                                 const u16* __restrict__ BT,
                                                 u16* __restrict__ C)
{
    __shared__ __attribute__((aligned(16))) u16 lsA[128][64];
    __shared__ __attribute__((aligned(16))) u16 lsB[128][64];
    const int tid  = threadIdx.x;
    const int lane = tid & 63;
    const int wv   = tid >> 6;
    const int wm   = wv >> 1, wn = wv & 1;
    const int m0   = blockIdx.x * 128;
    const int n0   = blockIdx.y * 128;
    const int fr   = lane & 15, fq = lane >> 4;
    const int srow = tid >> 3;
    const int sk8  = tid & 7;

    f32x4 acc[4][4] = {};

    for (int kt = 0; kt < 16; ++kt) {
        const int k0 = kt * 64;
#pragma unroll
        for (int it = 0; it < 4; ++it) {
            int row = srow + it * 32;
            int kg  = (sk8 ^ (row & 7)) * 8;
            uint4 va = *(const uint4*)(A  + (size_t)(m0 + row) * 1024 + k0 + kg);
            uint4 vb = *(const uint4*)(BT + (size_t)(n0 + row) * 1024 + k0 + kg);
            *(uint4*)&lsA[row][sk8 * 8] = va;
            *(uint4*)&lsB[row][sk8 * 8] = vb;
        }
        __syncthreads();
#pragma unroll
        for (int kc = 0; kc < 2; ++kc) {
            const int kb = kc * 32 + 8 * fq;
            bf16x8 af[4], bfv[4];
#pragma unroll
            for (int i = 0; i < 4; ++i) {
                int ra = 64 * wm + 16 * i + fr;
                af[i] = *(const bf16x8*)&lsA[ra][kb ^ ((ra & 7) * 8)];
            }
#pragma unroll
            for (int j = 0; j < 4; ++j) {
                int rb = 64 * wn + 16 * j + fr;
                bfv[j] = *(const bf16x8*)&lsB[rb][kb ^ ((rb & 7) * 8)];
            }
#pragma unroll
            for (int i = 0; i < 4; ++i)
#pragma unroll
                for (int j = 0; j < 4; ++j)
                    acc[i][j] = __builtin_amdgcn_mfma_f32_16x16x32_bf16(af[i], bfv[j], acc[i][j], 0, 0, 0);
        }
        __syncthreads();
    }
    // ---- epilogue: scatter into xproj[t][bg][cg][q][eb][ej] ----
#pragma unroll
    for (int i = 0; i < 4; ++i) {
        int grow = m0 + 64 * wm + 16 * i + 4 * fq;
#pragma unroll
        for (int j = 0; j < 4; ++j) {
            int gcol = n0 + 64 * wn + 16 * j + fr;
            int q  = gcol >> 10;
            int jg = gcol & 1023;
            int cg = jg >> 4, ej = jg & 15;
#pragma unroll
            for (int r = 0; r < 4; ++r) {
                int m = grow + r;
                int t = m >> 6, b = m & 63;
                int bg = b >> 4, eb = b & 15;
                size_t idx = ((((size_t)t * 4 + bg) * 64 + cg) * 4 + q) * 256 + eb * 16 + ej;
                C[idx] = f2bf(acc[i][j][r]);
            }
        }
    }
}

// ---------------------------------------------------------------------------
// K4: persistent LSTM scan.
// 256 WGs x 512 thr.  WG = (bg 0..3, cg 0..63): batches bg*16..+15, h-cols cg*16..+15.
// LDS: Wh slice [64 gate-rows][1024] bf16 swizzled (128KB) + partials (16KB)
//  -> 1 WG/CU, grid == 256 CUs, spin barrier safe.
// Waves = 8 K-slices of 128; each computes all 4 gates.
// Sync per step: waves 0-3 drain h stores -> barrier -> tid0 atomicAdd(bg ctr)
//  -> wave4 lane0 polls ctr (1 load/iter) -> acquire fence -> barrier.
// ---------------------------------------------------------------------------
__global__ __launch_bounds__(512, 1) void k_scan(const u16* __restrict__ xproj,  // [512][4][64][4][16][16]
                                                 const u16* __restrict__ whT,    // [4096][1024]
                                                 const float* __restrict__ bias, // [4096]
                                                 const float* __restrict__ C0,   // [64][1024]
                                                 u16* __restrict__ hbuf,         // [2][64][1024]
                                                 u32* __restrict__ ctr,          // [4][64] (bg at *64)
                                                 float* __restrict__ out)        // outputs|Hf|Cf
{
    __shared__ __attribute__((aligned(16))) u16   lds_w[64][1024];    // 128 KB
    __shared__ __attribute__((aligned(16))) float lds_p[4][4][16][16]; // 16 KB

    const int wg  = blockIdx.x;
    const int bg  = wg >> 6;          // batch group 0..3
    const int cg  = wg & 63;          // col group   0..63
    const int b0  = bg * 16;
    const int j0  = cg * 16;
    const int tid = threadIdx.x;
    const int lane = tid & 63;
    const int wv  = tid >> 6;         // 0..7 = K-slice
    const int fr  = lane & 15;
    const int fq  = lane >> 4;

    // ---- load Wh slice into LDS, swizzled: elem (n,k) at [n][k ^ ((n&7)*8)] ----
    for (int it = 0; it < 16; ++it) {
        int idx = tid + it * 512;               // uint4 index, 8192 total
        int row = idx >> 7;                     // 0..63   (gate*16 + jj)
        int k8  = idx & 127;
        int gg  = row >> 4, jj = row & 15;
        uint4 v = *((const uint4*)(whT + ((size_t)(gg * 1024 + j0 + jj) << 10)) + k8);
        *(uint4*)&lds_w[row][(k8 * 8) ^ ((row & 7) * 8)] = v;
    }

    // ---- per-thread recurrent state (threads 0..255) ----
    const int eb = tid >> 4;   // local batch 0..15
    const int ej = tid & 15;   // local h-col 0..15
    float c_state = 0.f;
    float bia[4] = {0.f, 0.f, 0.f, 0.f};
    if (tid < 256) {
        c_state = C0[(size_t)(b0 + eb) * 1024 + j0 + ej];
#pragma unroll
        for (int q = 0; q < 4; ++q) bia[q] = bias[q * 1024 + j0 + ej];
    }
    __syncthreads();

    const int ks = wv;                            // K-slice: cols ks*128..+127
    u32* ctr_bg = ctr + bg * 64;                  // 256B-spaced bg counters
    // per-WG xproj base (contiguous 2KB block per step, stride 2KB*256)
    const u16* xbase = xproj + (((size_t)bg * 64 + cg) * 1024) + eb * 16 + ej;

    for (int t = 0; t < 512; ++t) {
        const int p = t & 1;
        const u16* hb = hbuf + (size_t)p * 65536;

        // ---- A-frags: CACHED coalesced h loads (L2 serves the broadcast) ----
        union { bf16x8 v[4]; uint4 q[4]; } afu;
        {
            const u16* hp = hb + (size_t)(b0 + fr) * 1024 + ks * 128 + 8 * fq;
#pragma unroll
            for (int kk = 0; kk < 4; ++kk)
                afu.q[kk] = *(const uint4*)(hp + kk * 32);
        }

        // ---- xg prefetch (contiguous 2KB block; full-line fetches) ----
        float xg[4] = {0.f, 0.f, 0.f, 0.f};
        if (tid < 256) {
            const u16* xp = xbase + (size_t)t * 262144;   // 4*64*1024 elems/step
#pragma unroll
            for (int q = 0; q < 4; ++q) xg[q] = bf2f(xp[q * 256]);
        }

        // ---- MFMA: 4 gates x 4 k-chunks on this wave's K-slice ----
        f32x4 acc[4] = {};
#pragma unroll
        for (int g = 0; g < 4; ++g) {
            const int row = g * 16 + fr;
            const int swz = (row & 7) * 8;
#pragma unroll
            for (int kk = 0; kk < 4; ++kk) {
                bf16x8 bv = *(const bf16x8*)&lds_w[row][(ks * 128 + kk * 32 + 8 * fq) ^ swz];
                acc[g] = __builtin_amdgcn_mfma_f32_16x16x32_bf16(afu.v[kk], bv, acc[g], 0, 0, 0);
            }
        }

        // ---- phased cross-wave reduction (C layout: row=4*fq+r, col=fr) ----
        if (wv >= 4) {
#pragma unroll
            for (int g = 0; g < 4; ++g)
#pragma unroll
                for (int r = 0; r < 4; ++r)
                    lds_p[wv - 4][g][4 * fq + r][fr] = acc[g][r];
        }
        __syncthreads();
        if (wv < 4) {
#pragma unroll
            for (int g = 0; g < 4; ++g)
#pragma unroll
                for (int r = 0; r < 4; ++r)
                    lds_p[wv][g][4 * fq + r][fr] += acc[g][r];
        }
        __syncthreads();

        // ---- elementwise LSTM cell (threads 0..255) + h publish ----
        if (tid < 256) {
            float gate[4];
#pragma unroll
            for (int q = 0; q < 4; ++q)
                gate[q] = lds_p[0][q][eb][ej] + lds_p[1][q][eb][ej]
                        + lds_p[2][q][eb][ej] + lds_p[3][q][eb][ej] + xg[q] + bia[q];
            float i_ = sigm(gate[0]);
            float f_ = sigm(gate[1]);
            float o_ = sigm(gate[2]);
            float g_ = tanh_f(gate[3]);
            c_state = f_ * c_state + i_ * g_;
            float h_ = o_ * tanh_f(c_state);

            size_t hidx = (size_t)(b0 + eb) * 1024 + j0 + ej;

            // h -> write-through coherent buffer, packed 8B per 4 lanes
            u32 lo = (u32)f2bf(h_) | ((u32)f2bf(__shfl_down(h_, 1)) << 16);     // even ej
            u64 qv = (u64)lo | ((u64)(u32)__shfl_down((int)lo, 2) << 32);       // ej%4==0
            if ((ej & 3) == 0)
                __hip_atomic_store((u64*)(hbuf + (size_t)(p ^ 1) * 65536 + hidx), qv,
                                   __ATOMIC_RELAXED, __HIP_MEMORY_SCOPE_AGENT);
            // drain h stores to the coherence point BEFORE the arrive barrier
            asm volatile("s_waitcnt vmcnt(0)" ::: "memory");

            // out stores after the drain (their latency is off the sync path)
            out[(size_t)t * 65536 + hidx] = h_;
            if (t == 511) {
                out[(size_t)33554432 + hidx] = h_;              // Hf
                out[(size_t)33554432 + 65536 + hidx] = c_state; // Cf
            }
        }

        // ---- arrive: all h stores drained -> one atomicAdd per WG ----
        __syncthreads();
        if (tid == 0)
            atomicAdd(ctr_bg, 1u);

        // ---- wait: single-lane poll of the bg epoch counter ----
        if (wv == 4) {
            if (lane == 0) {
                const u32 tgt = (u32)(t + 1) * 64u;
                while (__hip_atomic_load(ctr_bg, __ATOMIC_RELAXED, __HIP_MEMORY_SCOPE_AGENT) < tgt)
                    __builtin_amdgcn_s_sleep(1);
            }
            // acquire: invalidate stale L1/L2 lines (no writeback) so next
            // step's cached h loads see the write-through data.
            __builtin_amdgcn_fence(__ATOMIC_ACQUIRE, "agent");
        }
        __syncthreads();
    }
}

// ---------------------------------------------------------------------------
// Workspace layout (bytes):
//   xproj  @ 0          : 268,435,456  (bf16 [512][4][64][4][16][16])
//   inb    @ 268435456  :  67,108,864  (bf16 inputs)
//   wxT    @ 335544320  :   8,388,608
//   whT    @ 343932928  :   8,388,608
//   bias   @ 352321536  :      16,384  (fp32 [4096])
//   hbuf   @ 352337920  :     262,144  (bf16 [2][64][1024])
//   ctr    @ 352600064  :       4,096
// ---------------------------------------------------------------------------
extern "C" void kernel_launch(void* const* d_in, const int* in_sizes, int n_in,
                              void* d_out, int out_size, void* d_ws, size_t ws_size,
                              hipStream_t stream)
{
    const float* inputs = (const float*)d_in[0];
    const float* H0     = (const float*)d_in[1];
    const float* C0     = (const float*)d_in[2];
    const float* Wx[4]  = {(const float*)d_in[3], (const float*)d_in[6],
                           (const float*)d_in[9], (const float*)d_in[12]};
    const float* Wh[4]  = {(const float*)d_in[4], (const float*)d_in[7],
                           (const float*)d_in[10], (const float*)d_in[13]};
    const float* bs[4]  = {(const float*)d_in[5], (const float*)d_in[8],
                           (const float*)d_in[11], (const float*)d_in[14]};

    char* ws = (char*)d_ws;
    u16*  xproj = (u16*)(ws);
    u16*  inb   = (u16*)(ws + 268435456);
    u16*  wxT   = (u16*)(ws + 335544320);
    u16*  whT   = (u16*)(ws + 343932928);
    float* bias = (float*)(ws + 352321536);
    u16*  hbuf  = (u16*)(ws + 352337920);
    u32*  ctr   = (u32*)(ws + 352600064);
    float* out  = (float*)d_out;

    k_init<<<dim3(64), dim3(256), 0, stream>>>(H0, bs[0], bs[1], bs[2], bs[3], hbuf, bias, ctr);
    k_cvt<<<dim3(32768), dim3(256), 0, stream>>>((const float4*)inputs, (ushort4*)inb);
    k_wt<<<dim3(32, 32, 8), dim3(32, 8), 0, stream>>>(Wx[0], Wx[1], Wx[2], Wx[3],
                                                      Wh[0], Wh[1], Wh[2], Wh[3], wxT, whT);
    k_gemm<<<dim3(256, 32), dim3(256), 0, stream>>>(inb, wxT, xproj);
    k_scan<<<dim3(256), dim3(512), 0, stream>>>(xproj, whT, bias, C0, hbuf, ctr, out);
}

// Round 7
// 3538.898 us; speedup vs baseline: 6.2582x; 1.0527x over previous
//
#include <hip/hip_runtime.h>

// ============================================================================
// LSTM scan, T=512 B=64 D=H=1024.
//   K0 k_init : zero counters, bias concat, H0 -> bf16 hbuf0
//   K1 k_cvt  : inputs fp32 -> bf16
//   K2 k_wt   : 8x transpose+cvt weights -> WxT/WhT [4096][1024] bf16
//   K3 k_gemm : x_proj = inputs @ Wx (bf16 MFMA, 128x128x64), epilogue writes
//               scan-friendly layout xproj[t][bg][cg][q][eb][ej] (2KB/WG/step)
//   K4 k_scan : persistent 256 WGs (4 batch-groups x 64 col-groups).
//               h[t+1] -> 512-deep VIRGIN buffer (dead inb space): addresses
//               never reused => cached consumer loads can never be stale =>
//               NO per-step fence/L2-invalidate. Producers write-through
//               (agent-scope relaxed); L2 serves the 64-way broadcast.
//               Raw s_barriers in the loop (no implicit vmcnt(0) drains);
//               per-bg epoch counter arrive + single-lane poll.
// ============================================================================

typedef unsigned short u16;
typedef unsigned int   u32;
typedef unsigned long long u64;
typedef __attribute__((ext_vector_type(8))) short bf16x8;   // 8 bf16 in 4 VGPRs
typedef __attribute__((ext_vector_type(4))) float f32x4;

__device__ __forceinline__ float bf2f(u16 u) {
    union { u32 i; float f; } v; v.i = ((u32)u) << 16; return v.f;
}
__device__ __forceinline__ u16 f2bf(float f) {   // round-to-nearest-even
    union { float f; u32 u; } v; v.f = f;
    u32 u = v.u;
    return (u16)((u + 0x7FFFu + ((u >> 16) & 1u)) >> 16);
}
__device__ __forceinline__ float sigm(float x)   { return 1.f / (1.f + __expf(-x)); }
__device__ __forceinline__ float tanh_f(float x) { return 1.f - 2.f / (1.f + __expf(2.f * x)); }

// raw barriers: avoid __syncthreads' implicit vmcnt(0) drain
#define BAR_LGKM() asm volatile("s_waitcnt lgkmcnt(0)\n\ts_barrier" ::: "memory")
#define BAR_RAW()  asm volatile("s_barrier" ::: "memory")

// ---------------------------------------------------------------------------
// K0: init — hbuf0 = bf16(H0); bias concat [i|f|o|c]; zero counters.
// grid 64 x 256
// ---------------------------------------------------------------------------
__global__ void k_init(const float* __restrict__ H0,
                       const float* __restrict__ bi, const float* __restrict__ bff,
                       const float* __restrict__ bo, const float* __restrict__ bc,
                       u16* __restrict__ hbuf0, float* __restrict__ bias,
                       u32* __restrict__ ctr)
{
    int i = blockIdx.x * 256 + threadIdx.x;      // 0..16383
#pragma unroll
    for (int r = 0; r < 4; ++r) {
        int idx = i + r * 16384;                 // 0..65535
        hbuf0[idx] = f2bf(H0[idx]);
    }
    if (i < 4096) {
        const float* bp = (i < 1024) ? bi : (i < 2048) ? bff : (i < 3072) ? bo : bc;
        bias[i] = bp[i & 1023];
    }
    if (i < 1024) ctr[i] = 0u;                   // bg counters at ctr[bg*64]
}

// ---------------------------------------------------------------------------
// K1: inputs fp32 -> bf16 (33.5M elems). grid 32768 x 256, 1 float4/thread.
// ---------------------------------------------------------------------------
__global__ void k_cvt(const float4* __restrict__ in, ushort4* __restrict__ out)
{
    size_t i = (size_t)blockIdx.x * 256 + threadIdx.x;
    float4 v = in[i];
    ushort4 o;
    o.x = f2bf(v.x); o.y = f2bf(v.y); o.z = f2bf(v.z); o.w = f2bf(v.w);
    out[i] = o;
}

// ---------------------------------------------------------------------------
// K2: weight transpose+cvt.  src [1024][1024] fp32 row-major (k-major) ->
// dst [1024][1024] bf16 with rows = output cols.
// grid (32,32,8), block (32,8). z<4 -> WxT gate z ; z>=4 -> WhT gate z-4.
// ---------------------------------------------------------------------------
__global__ void k_wt(const float* s0, const float* s1, const float* s2, const float* s3,
                     const float* s4, const float* s5, const float* s6, const float* s7,
                     u16* __restrict__ wxT, u16* __restrict__ whT)
{
    const float* srcs[8] = {s0, s1, s2, s3, s4, s5, s6, s7};
    int z = blockIdx.z;
    const float* src = srcs[z];
    u16* dst = (z < 4) ? (wxT + (size_t)z * 1048576) : (whT + (size_t)(z - 4) * 1048576);
    __shared__ float tile[32][33];
    int k0 = blockIdx.x * 32, n0 = blockIdx.y * 32;
    int tx = threadIdx.x, ty = threadIdx.y;
#pragma unroll
    for (int s = 0; s < 4; ++s)
        tile[ty + 8 * s][tx] = src[(size_t)(k0 + ty + 8 * s) * 1024 + n0 + tx];
    __syncthreads();
#pragma unroll
    for (int s = 0; s < 4; ++s)
        dst[(size_t)(n0 + ty + 8 * s) * 1024 + k0 + tx] = f2bf(tile[tx][ty + 8 * s]);
}

// ---------------------------------------------------------------------------
// K3: x_proj GEMM.  [32768][1024] @ [4096][1024]^T, bf16 MFMA 128x128x64.
// Epilogue writes xproj[t][bg][cg][q][eb][ej]: per (t, scan-WG) slice is one
// contiguous 2KB block -> full-line HBM fetches in the scan, no over-fetch.
// grid (256, 32), block 256.
// ---------------------------------------------------------------------------
__global__ __launch_bounds__(256, 2) void k_gemm(const u16* __restrict__ A,
                                                 const u16* __restrict__ BT,
                                                 u16* __restrict__ C)
{
    __shared__ __attribute__((aligned(16))) u16 lsA[128][64];
    __shared__ __attribute__((aligned(16))) u16 lsB[128][64];
    const int tid  = threadIdx.x;
    const int lane = tid & 63;
    const int wv   = tid >> 6;
    const int wm   = wv >> 1, wn = wv & 1;
    const int m0   = blockIdx.x * 128;
    const int n0   = blockIdx.y * 128;
    const int fr   = lane & 15, fq = lane >> 4;
    const int srow = tid >> 3;
    const int sk8  = tid & 7;

    f32x4 acc[4][4] = {};

    for (int kt = 0; kt < 16; ++kt) {
        const int k0 = kt * 64;
#pragma unroll
        for (int it = 0; it < 4; ++it) {
            int row = srow + it * 32;
            int kg  = (sk8 ^ (row & 7)) * 8;
            uint4 va = *(const uint4*)(A  + (size_t)(m0 + row) * 1024 + k0 + kg);
            uint4 vb = *(const uint4*)(BT + (size_t)(n0 + row) * 1024 + k0 + kg);
            *(uint4*)&lsA[row][sk8 * 8] = va;
            *(uint4*)&lsB[row][sk8 * 8] = vb;
        }
        __syncthreads();
#pragma unroll
        for (int kc = 0; kc < 2; ++kc) {
            const int kb = kc * 32 + 8 * fq;
            bf16x8 af[4], bfv[4];
#pragma unroll
            for (int i = 0; i < 4; ++i) {
                int ra = 64 * wm + 16 * i + fr;
                af[i] = *(const bf16x8*)&lsA[ra][kb ^ ((ra & 7) * 8)];
            }
#pragma unroll
            for (int j = 0; j < 4; ++j) {
                int rb = 64 * wn + 16 * j + fr;
                bfv[j] = *(const bf16x8*)&lsB[rb][kb ^ ((rb & 7) * 8)];
            }
#pragma unroll
            for (int i = 0; i < 4; ++i)
#pragma unroll
                for (int j = 0; j < 4; ++j)
                    acc[i][j] = __builtin_amdgcn_mfma_f32_16x16x32_bf16(af[i], bfv[j], acc[i][j], 0, 0, 0);
        }
        __syncthreads();
    }
    // ---- epilogue: scatter into xproj[t][bg][cg][q][eb][ej] ----
#pragma unroll
    for (int i = 0; i < 4; ++i) {
        int grow = m0 + 64 * wm + 16 * i + 4 * fq;
#pragma unroll
        for (int j = 0; j < 4; ++j) {
            int gcol = n0 + 64 * wn + 16 * j + fr;
            int q  = gcol >> 10;
            int jg = gcol & 1023;
            int cg = jg >> 4, ej = jg & 15;
#pragma unroll
            for (int r = 0; r < 4; ++r) {
                int m = grow + r;
                int t = m >> 6, b = m & 63;
                int bg = b >> 4, eb = b & 15;
                size_t idx = ((((size_t)t * 4 + bg) * 64 + cg) * 4 + q) * 256 + eb * 16 + ej;
                C[idx] = f2bf(acc[i][j][r]);
            }
        }
    }
}

// ---------------------------------------------------------------------------
// K4: persistent LSTM scan.
// 256 WGs x 512 thr.  WG = (bg 0..3, cg 0..63): batches bg*16..+15, h-cols cg*16..+15.
// LDS: Wh slice [64 gate-rows][1024] bf16 swizzled (128KB) + partials (16KB).
// Waves = 8 K-slices of 128; each computes all 4 gates.
// h[t+1] -> hseq[t] (virgin addresses; write-through agent stores; cached
// consumer loads; NO fences). Raw in-loop barriers. Per-bg epoch ctr sync.
// ---------------------------------------------------------------------------
__global__ __launch_bounds__(512, 1) void k_scan(const u16* __restrict__ xproj,  // [512][4][64][4][16][16]
                                                 const u16* __restrict__ whT,    // [4096][1024]
                                                 const float* __restrict__ bias, // [4096]
                                                 const float* __restrict__ C0,   // [64][1024]
                                                 const u16* __restrict__ hbuf0,  // [64][1024]  (h_0)
                                                 u16* __restrict__ hseq,         // [512][64][1024]
                                                 u32* __restrict__ ctr,          // [4][64] (bg at *64)
                                                 float* __restrict__ out)        // outputs|Hf|Cf
{
    __shared__ __attribute__((aligned(16))) u16   lds_w[64][1024];    // 128 KB
    __shared__ __attribute__((aligned(16))) float lds_p[4][4][16][16]; // 16 KB

    const int wg  = blockIdx.x;
    const int bg  = wg >> 6;          // batch group 0..3
    const int cg  = wg & 63;          // col group   0..63
    const int b0  = bg * 16;
    const int j0  = cg * 16;
    const int tid = threadIdx.x;
    const int lane = tid & 63;
    const int wv  = tid >> 6;         // 0..7 = K-slice
    const int fr  = lane & 15;
    const int fq  = lane >> 4;

    // ---- load Wh slice into LDS, swizzled: elem (n,k) at [n][k ^ ((n&7)*8)] ----
    for (int it = 0; it < 16; ++it) {
        int idx = tid + it * 512;               // uint4 index, 8192 total
        int row = idx >> 7;                     // 0..63   (gate*16 + jj)
        int k8  = idx & 127;
        int gg  = row >> 4, jj = row & 15;
        uint4 v = *((const uint4*)(whT + ((size_t)(gg * 1024 + j0 + jj) << 10)) + k8);
        *(uint4*)&lds_w[row][(k8 * 8) ^ ((row & 7) * 8)] = v;
    }

    // ---- per-thread recurrent state (threads 0..255) ----
    const int eb = tid >> 4;   // local batch 0..15
    const int ej = tid & 15;   // local h-col 0..15
    float c_state = 0.f;
    float bia[4] = {0.f, 0.f, 0.f, 0.f};
    if (tid < 256) {
        c_state = C0[(size_t)(b0 + eb) * 1024 + j0 + ej];
#pragma unroll
        for (int q = 0; q < 4; ++q) bia[q] = bias[q * 1024 + j0 + ej];
    }
    __syncthreads();

    const int ks = wv;                            // K-slice: cols ks*128..+127
    u32* ctr_bg = ctr + bg * 64;                  // 256B-spaced bg counters
    // per-WG xproj base (contiguous 2KB block per step, stride 512KB)
    const u16* xbase = xproj + (((size_t)bg * 64 + cg) * 1024) + eb * 16 + ej;

    for (int t = 0; t < 512; ++t) {
        // h_t source: step 0 from hbuf0, else virgin slot t-1
        const u16* hb = (t == 0) ? hbuf0 : (hseq + ((size_t)(t - 1) << 16));

        // ---- A-frags: CACHED coalesced h loads (L2 serves the broadcast) ----
        union { bf16x8 v[4]; uint4 q[4]; } afu;
        {
            const u16* hp = hb + (size_t)(b0 + fr) * 1024 + ks * 128 + 8 * fq;
#pragma unroll
            for (int kk = 0; kk < 4; ++kk)
                afu.q[kk] = *(const uint4*)(hp + kk * 32);
        }

        // ---- xg prefetch (contiguous 2KB block; consumed at elementwise) ----
        float xg[4] = {0.f, 0.f, 0.f, 0.f};
        if (tid < 256) {
            const u16* xp = xbase + (size_t)t * 262144;   // 4*64*1024 elems/step
#pragma unroll
            for (int q = 0; q < 4; ++q) xg[q] = bf2f(xp[q * 256]);
        }

        // ---- MFMA: 4 gates x 4 k-chunks on this wave's K-slice ----
        f32x4 acc[4] = {};
#pragma unroll
        for (int g = 0; g < 4; ++g) {
            const int row = g * 16 + fr;
            const int swz = (row & 7) * 8;
#pragma unroll
            for (int kk = 0; kk < 4; ++kk) {
                bf16x8 bv = *(const bf16x8*)&lds_w[row][(ks * 128 + kk * 32 + 8 * fq) ^ swz];
                acc[g] = __builtin_amdgcn_mfma_f32_16x16x32_bf16(afu.v[kk], bv, acc[g], 0, 0, 0);
            }
        }

        // ---- phased cross-wave reduction (C layout: row=4*fq+r, col=fr) ----
        if (wv >= 4) {
#pragma unroll
            for (int g = 0; g < 4; ++g)
#pragma unroll
                for (int r = 0; r < 4; ++r)
                    lds_p[wv - 4][g][4 * fq + r][fr] = acc[g][r];
        }
        BAR_LGKM();
        if (wv < 4) {
#pragma unroll
            for (int g = 0; g < 4; ++g)
#pragma unroll
                for (int r = 0; r < 4; ++r)
                    lds_p[wv][g][4 * fq + r][fr] += acc[g][r];
        }
        BAR_LGKM();

        // ---- elementwise LSTM cell (threads 0..255) + h publish ----
        if (tid < 256) {
            float gate[4];
#pragma unroll
            for (int q = 0; q < 4; ++q)
                gate[q] = lds_p[0][q][eb][ej] + lds_p[1][q][eb][ej]
                        + lds_p[2][q][eb][ej] + lds_p[3][q][eb][ej] + xg[q] + bia[q];
            float i_ = sigm(gate[0]);
            float f_ = sigm(gate[1]);
            float o_ = sigm(gate[2]);
            float g_ = tanh_f(gate[3]);
            c_state = f_ * c_state + i_ * g_;
            float h_ = o_ * tanh_f(c_state);

            size_t hidx = (size_t)(b0 + eb) * 1024 + j0 + ej;

            // h_{t+1} -> virgin slot t (write-through, packed 8B per 4 lanes)
            u32 lo = (u32)f2bf(h_) | ((u32)f2bf(__shfl_down(h_, 1)) << 16);     // even ej
            u64 qv = (u64)lo | ((u64)(u32)__shfl_down((int)lo, 2) << 32);       // ej%4==0
            if ((ej & 3) == 0)
                __hip_atomic_store((u64*)(hseq + ((size_t)t << 16) + hidx), qv,
                                   __ATOMIC_RELAXED, __HIP_MEMORY_SCOPE_AGENT);
            // drain h stores to the coherence point BEFORE the arrive barrier
            asm volatile("s_waitcnt vmcnt(0)" ::: "memory");

            // out stores after the drain; raw barriers let their acks float
            out[(size_t)t * 65536 + hidx] = h_;
            if (t == 511) {
                out[(size_t)33554432 + hidx] = h_;              // Hf
                out[(size_t)33554432 + 65536 + hidx] = c_state; // Cf
            }
        }

        // ---- arrive: h drained by all producer waves -> 1 atomicAdd per WG ----
        BAR_RAW();
        if (tid == 0)
            atomicAdd(ctr_bg, 1u);

        // ---- wait: single-lane poll of the bg epoch counter (no fence) ----
        if (wv == 4 && lane == 0) {
            const u32 tgt = (u32)(t + 1) * 64u;
            while (__hip_atomic_load(ctr_bg, __ATOMIC_RELAXED, __HIP_MEMORY_SCOPE_AGENT) < tgt) {}
        }
        BAR_RAW();
    }
}

// ---------------------------------------------------------------------------
// Workspace layout (bytes):
//   xproj  @ 0          : 268,435,456  (bf16 [512][4][64][4][16][16])
//   inb    @ 268435456  :  67,108,864  (bf16 inputs; DEAD after k_gemm ->
//                                       reused as hseq[512][64][1024] bf16)
//   wxT    @ 335544320  :   8,388,608
//   whT    @ 343932928  :   8,388,608
//   bias   @ 352321536  :      16,384  (fp32 [4096])
//   hbuf0  @ 352337920  :     131,072  (bf16 [64][1024], h_0)
//   ctr    @ 352600064  :       4,096
// ---------------------------------------------------------------------------
extern "C" void kernel_launch(void* const* d_in, const int* in_sizes, int n_in,
                              void* d_out, int out_size, void* d_ws, size_t ws_size,
                              hipStream_t stream)
{
    const float* inputs = (const float*)d_in[0];
    const float* H0     = (const float*)d_in[1];
    const float* C0     = (const float*)d_in[2];
    const float* Wx[4]  = {(const float*)d_in[3], (const float*)d_in[6],
                           (const float*)d_in[9], (const float*)d_in[12]};
    const float* Wh[4]  = {(const float*)d_in[4], (const float*)d_in[7],
                           (const float*)d_in[10], (const float*)d_in[13]};
    const float* bs[4]  = {(const float*)d_in[5], (const float*)d_in[8],
                           (const float*)d_in[11], (const float*)d_in[14]};

    char* ws = (char*)d_ws;
    u16*  xproj = (u16*)(ws);
    u16*  inb   = (u16*)(ws + 268435456);     // doubles as hseq after k_gemm
    u16*  wxT   = (u16*)(ws + 335544320);
    u16*  whT   = (u16*)(ws + 343932928);
    float* bias = (float*)(ws + 352321536);
    u16*  hbuf0 = (u16*)(ws + 352337920);
    u32*  ctr   = (u32*)(ws + 352600064);
    float* out  = (float*)d_out;

    k_init<<<dim3(64), dim3(256), 0, stream>>>(H0, bs[0], bs[1], bs[2], bs[3], hbuf0, bias, ctr);
    k_cvt<<<dim3(32768), dim3(256), 0, stream>>>((const float4*)inputs, (ushort4*)inb);
    k_wt<<<dim3(32, 32, 8), dim3(32, 8), 0, stream>>>(Wx[0], Wx[1], Wx[2], Wx[3],
                                                      Wh[0], Wh[1], Wh[2], Wh[3], wxT, whT);
    k_gemm<<<dim3(256, 32), dim3(256), 0, stream>>>(inb, wxT, xproj);
    k_scan<<<dim3(256), dim3(512), 0, stream>>>(xproj, whT, bias, C0, hbuf0, inb, ctr, out);
}